// Round 1
// baseline (695.666 us; speedup 1.0000x reference)
//
#include <hip/hip_runtime.h>

#define TREES 64
#define NN 63        // internal nodes per tree
#define LL 64        // leaves per tree
#define CC 100       // classes
#define DD 512       // feature dim
#define BB 8192      // batch
#define BT 128       // rows per block
#define BK 16        // K tile

// ---------------------------------------------------------------------------
// Kernel 1: W2[t,l,c] = tree_w[t] * softmax(leaf_logits[t,l,:])[c]
// one wave per (t,l) row; block = 4 waves
// ---------------------------------------------------------------------------
__global__ __launch_bounds__(256) void prep_w2_kernel(
    const float* __restrict__ leaf_logits,
    const float* __restrict__ tree_w,
    float* __restrict__ w2)
{
    int row  = blockIdx.x * 4 + (threadIdx.x >> 6);   // 0..4095  (= t*64 + l)
    int lane = threadIdx.x & 63;
    const float* src = leaf_logits + (size_t)row * CC;
    float v0 = (lane < CC)      ? src[lane]      : -1e30f;
    float v1 = (lane + 64 < CC) ? src[lane + 64] : -1e30f;
    float m = fmaxf(v0, v1);
#pragma unroll
    for (int off = 32; off > 0; off >>= 1)
        m = fmaxf(m, __shfl_down(m, off, 64));
    m = __shfl(m, 0, 64);
    float e0 = (lane < CC)      ? __expf(v0 - m) : 0.f;
    float e1 = (lane + 64 < CC) ? __expf(v1 - m) : 0.f;
    float s = e0 + e1;
#pragma unroll
    for (int off = 32; off > 0; off >>= 1)
        s += __shfl_down(s, off, 64);
    s = __shfl(s, 0, 64);
    float scale = tree_w[row >> 6] / s;
    float* dst = w2 + (size_t)row * CC;
    if (lane < CC)      dst[lane]      = e0 * scale;
    if (lane + 64 < CC) dst[lane + 64] = e1 * scale;
}

// ---------------------------------------------------------------------------
// Kernel 2: fused  dec-GEMM -> sigmoid -> leaf probs -> partial out (atomic)
// grid = (B/BT, TREES); block = 256 threads (tx 0..15 = node/leaf/col group,
// ty 0..15 = row group of 8)
// ---------------------------------------------------------------------------
__global__ __launch_bounds__(256) void forest_kernel(
    const float* __restrict__ x,     // [B][D]
    const float* __restrict__ sw,    // [T][63][D]
    const float* __restrict__ sb,    // [T][63]
    const float* __restrict__ w2,    // [T*64][100]  (ws)
    float* __restrict__ out)         // [B][100]
{
    __shared__ float xs[BK][BT + 4];   // k-major x tile   [16][132]  8.4 KB
    __shared__ float wsm[BK][68];      // k-major w tile   [16][68]   4.3 KB
    __shared__ float dl[8448];         // dec [128][65] then lp [64][132] 33.8 KB
    __shared__ float bias_s[64];

    const int tid = threadIdx.x;
    const int tx  = tid & 15;
    const int ty  = tid >> 4;
    const int b0  = blockIdx.x * BT;
    const int t   = blockIdx.y;

    if (tid < NN) bias_s[tid] = sb[t * NN + tid];
    if (tid == NN) bias_s[NN] = 0.f;

    float acc[8][4];
#pragma unroll
    for (int i = 0; i < 8; ++i)
#pragma unroll
        for (int j = 0; j < 4; ++j) acc[i][j] = 0.f;

    // staging-load thread mapping: lr = row(0..63 then +64), lc = float4 slot
    const int lr = tid >> 2;
    const int lc = tid & 3;
    const float* xp0 = x + (size_t)(b0 + lr) * DD + lc * 4;
    const float* xp1 = x + (size_t)(b0 + lr + 64) * DD + lc * 4;
    const int wn = (tid < 252) ? (tid >> 2) : 0;        // node for weight load
    const float* wp = sw + ((size_t)t * NN + wn) * DD + lc * 4;

    float4 v0 = *(const float4*)(xp0);
    float4 v1 = *(const float4*)(xp1);
    float4 w4 = *(const float4*)(wp);

    for (int k0 = 0; k0 < DD; k0 += BK) {
        __syncthreads();   // previous tile's reads done
        xs[lc * 4 + 0][lr] = v0.x;  xs[lc * 4 + 1][lr] = v0.y;
        xs[lc * 4 + 2][lr] = v0.z;  xs[lc * 4 + 3][lr] = v0.w;
        xs[lc * 4 + 0][lr + 64] = v1.x;  xs[lc * 4 + 1][lr + 64] = v1.y;
        xs[lc * 4 + 2][lr + 64] = v1.z;  xs[lc * 4 + 3][lr + 64] = v1.w;
        if (tid < 252) {
            wsm[lc * 4 + 0][wn] = w4.x;  wsm[lc * 4 + 1][wn] = w4.y;
            wsm[lc * 4 + 2][wn] = w4.z;  wsm[lc * 4 + 3][wn] = w4.w;
        } else {
            int q = tid - 252;
#pragma unroll
            for (int i = 0; i < 4; ++i) wsm[q * 4 + i][NN] = 0.f;
        }
        __syncthreads();
        if (k0 + BK < DD) {            // prefetch next tile under compute
            v0 = *(const float4*)(xp0 + k0 + BK);
            v1 = *(const float4*)(xp1 + k0 + BK);
            w4 = *(const float4*)(wp  + k0 + BK);
        }
#pragma unroll
        for (int kk = 0; kk < BK; ++kk) {
            float4 a0 = *(const float4*)&xs[kk][ty * 8];
            float4 a1 = *(const float4*)&xs[kk][ty * 8 + 4];
            float4 bv = *(const float4*)&wsm[kk][tx * 4];
            float av[8] = {a0.x, a0.y, a0.z, a0.w, a1.x, a1.y, a1.z, a1.w};
            float bb[4] = {bv.x, bv.y, bv.z, bv.w};
#pragma unroll
            for (int i = 0; i < 8; ++i)
#pragma unroll
                for (int j = 0; j < 4; ++j)
                    acc[i][j] = fmaf(av[i], bb[j], acc[i][j]);
        }
    }

    // --- sigmoid -> dec staged in LDS, stride 65 ---
#pragma unroll
    for (int i = 0; i < 8; ++i) {
        int r = ty * 8 + i;
#pragma unroll
        for (int j = 0; j < 4; ++j) {
            float logit = acc[i][j] + bias_s[tx * 4 + j];
            float dv = 1.f / (1.f + __expf(-logit));
            dl[r * 65 + tx * 4 + j] = dv;
        }
    }
    __syncthreads();

    // --- leaf probs: leaves l = tx*4 + j, rows r = ty*8 + i ---
    // path: d0:n=0,bit=(l>>5); d1:n=1+(l>>5),bit=(l>>4); d2:n=3+(l>>4),bit=(l>>3)
    //       d3:n=7+(l>>3),bit=(l>>2); d4:n=15+(l>>2),bit=(l>>1); d5:n=31+(l>>1),bit=l&1
    const int n1 = 1 + (tx >> 3);
    const int n2 = 3 + (tx >> 2);
    const int n3 = 7 + (tx >> 1);
    const int bb0 = (tx >> 3) & 1;
    const int bb1 = (tx >> 2) & 1;
    const int bb2 = (tx >> 1) & 1;
    const int bb3 = tx & 1;
    float lp[8][4];
#pragma unroll
    for (int i = 0; i < 8; ++i) {
        int r = ty * 8 + i;
        const float* dr = &dl[r * 65];
        float d0 = dr[0], d1 = dr[n1], d2 = dr[n2], d3 = dr[n3];
        float pre = (bb0 ? d0 : 1.f - d0) * (bb1 ? d1 : 1.f - d1)
                  * (bb2 ? d2 : 1.f - d2) * (bb3 ? d3 : 1.f - d3);
        float d4  = dr[15 + tx];
        float d5a = dr[31 + tx * 2];
        float d5b = dr[31 + tx * 2 + 1];
        lp[i][0] = pre * (1.f - d4) * (1.f - d5a);
        lp[i][1] = pre * (1.f - d4) * d5a;
        lp[i][2] = pre * d4 * (1.f - d5b);
        lp[i][3] = pre * d4 * d5b;
    }
    __syncthreads();   // all dec reads done before overwrite

    // --- store lp transposed: lp_s[l][r], stride 132 (reuses dl) ---
#pragma unroll
    for (int j = 0; j < 4; ++j) {
        int l = tx * 4 + j;
#pragma unroll
        for (int i = 0; i < 8; ++i)
            dl[l * 132 + ty * 8 + i] = lp[i][j];
    }
    __syncthreads();

    // --- GEMM2: po[r][c] = sum_l lp[l][r] * w2[t*64+l][c] ---
    const float* w2p = w2 + (size_t)t * LL * CC;
    float po[8][7];
#pragma unroll
    for (int i = 0; i < 8; ++i)
#pragma unroll
        for (int jj = 0; jj < 7; ++jj) po[i][jj] = 0.f;

    for (int l = 0; l < LL; ++l) {
        float4 u0 = *(const float4*)&dl[l * 132 + ty * 8];
        float4 u1 = *(const float4*)&dl[l * 132 + ty * 8 + 4];
        float lv[8] = {u0.x, u0.y, u0.z, u0.w, u1.x, u1.y, u1.z, u1.w};
#pragma unroll
        for (int jj = 0; jj < 7; ++jj) {
            int c = jj * 16 + tx;
            float wv = (c < CC) ? w2p[l * CC + c] : 0.f;
#pragma unroll
            for (int i = 0; i < 8; ++i)
                po[i][jj] = fmaf(lv[i], wv, po[i][jj]);
        }
    }

#pragma unroll
    for (int jj = 0; jj < 7; ++jj) {
        int c = jj * 16 + tx;
        if (c < CC) {
#pragma unroll
            for (int i = 0; i < 8; ++i)
                atomicAdd(&out[(size_t)(b0 + ty * 8 + i) * CC + c], po[i][jj]);
        }
    }
}

// ---------------------------------------------------------------------------
extern "C" void kernel_launch(void* const* d_in, const int* in_sizes, int n_in,
                              void* d_out, int out_size, void* d_ws, size_t ws_size,
                              hipStream_t stream) {
    const float* x  = (const float*)d_in[0];   // [8192][512]
    const float* sw = (const float*)d_in[1];   // [64][63][512]
    const float* sb = (const float*)d_in[2];   // [64][63]
    const float* ll = (const float*)d_in[3];   // [64][64][100]
    const float* tw = (const float*)d_in[4];   // [64]
    float* out = (float*)d_out;                // [8192][100]
    float* w2  = (float*)d_ws;                 // [64*64][100] = 1.64 MB scratch

    hipMemsetAsync(d_out, 0, (size_t)out_size * sizeof(float), stream);
    prep_w2_kernel<<<dim3(TREES * LL / 4), 256, 0, stream>>>(ll, tw, w2);
    forest_kernel<<<dim3(BB / BT, TREES), 256, 0, stream>>>(x, sw, sb, w2, out);
}

// Round 2
// 289.857 us; speedup vs baseline: 2.4000x; 2.4000x over previous
//
#include <hip/hip_runtime.h>

#define TREES 64
#define NN 63        // internal nodes per tree
#define LL 64        // leaves per tree
#define CC 100       // classes
#define CPAD 112     // classes padded to 7*16
#define DD 512       // feature dim
#define BB 8192      // batch
#define BM 128       // rows per block
#define BK 32        // K tile

typedef __attribute__((ext_vector_type(8))) _Float16 f16x8;
typedef __attribute__((ext_vector_type(4))) float floatx4;

// LDS strides (in f16 elements) chosen for bank-conflict-free b128 frag reads:
// XS/WS stride 40 (80 B, bank step 20 -> 2-way, free); LP stride 72 (144 B,
// step 4 -> 2-way); DEC stride 130 (260 B, step 1 -> conflict-free scalar).
#define XSTR 40
#define LPSTR 72
#define DSTR 130
#define XS_OFF 0                 // 128*40*2 = 10240
#define WL_OFF 10240             // 128*40*2 = 10240   (staging total 20480)
#define LP_OFF 0                 // aliases staging: 128*72*2 = 18432 <= 20480
#define DEC_OFF 20480            // 128*130*2 = 33280
#define BIAS_OFF 53760           // 128*4 = 512
#define SMEM_BYTES 54272

// ---------------------------------------------------------------------------
// Kernel 1: w2T[t][c][l] = f16( tree_w[t] * softmax(leaf_logits[t,l,:])[c] )
// transposed + class-padded to 112 so it can be read directly as MFMA B-frags.
// one wave per (t,l); block = 4 waves
// ---------------------------------------------------------------------------
__global__ __launch_bounds__(256) void prep_w2_kernel(
    const float* __restrict__ leaf_logits,
    const float* __restrict__ tree_w,
    _Float16* __restrict__ w2T)
{
    int row  = blockIdx.x * 4 + (threadIdx.x >> 6);   // 0..4095 (= t*64 + l)
    int lane = threadIdx.x & 63;
    int t = row >> 6, l = row & 63;
    const float* src = leaf_logits + (size_t)row * CC;
    float v0 = (lane < CC)      ? src[lane]      : -1e30f;
    float v1 = (lane + 64 < CC) ? src[lane + 64] : -1e30f;
    float m = fmaxf(v0, v1);
#pragma unroll
    for (int off = 32; off > 0; off >>= 1)
        m = fmaxf(m, __shfl_down(m, off, 64));
    m = __shfl(m, 0, 64);
    float e0 = (lane < CC)      ? __expf(v0 - m) : 0.f;
    float e1 = (lane + 64 < CC) ? __expf(v1 - m) : 0.f;
    float s = e0 + e1;
#pragma unroll
    for (int off = 32; off > 0; off >>= 1)
        s += __shfl_down(s, off, 64);
    s = __shfl(s, 0, 64);
    float scale = tree_w[t] / s;
    _Float16* base = w2T + (size_t)t * CPAD * LL;
    if (lane < CC)      base[(size_t)lane * LL + l]        = (_Float16)(e0 * scale);
    if (lane + 64 < CC) base[(size_t)(lane + 64) * LL + l] = (_Float16)(e1 * scale);
    if (lane < CPAD - CC) base[(size_t)(CC + lane) * LL + l] = (_Float16)0.f;
}

// ---------------------------------------------------------------------------
// Kernel 2: fused fp16-MFMA dec-GEMM -> sigmoid -> leaf probs -> MFMA GEMM2
// grid = (B/BM, TREES/2); block = 256 (4 waves in 2x2 grid, wave tile 64x64)
// ---------------------------------------------------------------------------
__global__ __launch_bounds__(256, 3) void forest_kernel(
    const float* __restrict__ x,     // [B][D]
    const float* __restrict__ sw,    // [T][63][D]
    const float* __restrict__ sb,    // [T][63]
    const _Float16* __restrict__ w2T,// [T][112][64]  (ws)
    float* __restrict__ out)         // [B][100]
{
    __shared__ __align__(16) char smem[SMEM_BYTES];
    _Float16* xs   = (_Float16*)(smem + XS_OFF);
    _Float16* wl   = (_Float16*)(smem + WL_OFF);
    _Float16* lp   = (_Float16*)(smem + LP_OFF);
    _Float16* dec  = (_Float16*)(smem + DEC_OFF);
    float*    bias_s = (float*)(smem + BIAS_OFF);

    const int tid  = threadIdx.x;
    const int lane = tid & 63;
    const int wid  = tid >> 6;
    const int wy   = wid >> 1;      // wave row group
    const int wx   = wid & 1;       // wave col group (tree within pair)
    const int quad = lane >> 4;     // 0..3
    const int l15  = lane & 15;
    const int b0   = blockIdx.x * BM;
    const int t0   = blockIdx.y * 2;

    // bias for 128 cols (2 trees x 64 padded nodes)
    if (tid < 128) {
        int tr = t0 + (tid >> 6), nd = tid & 63;
        bias_s[tid] = (nd < NN) ? sb[tr * NN + nd] : 0.f;
    }

    floatx4 acc[4][4];
#pragma unroll
    for (int i = 0; i < 4; ++i)
#pragma unroll
        for (int j = 0; j < 4; ++j) acc[i][j] = (floatx4)0.f;

    // staging mapping: each thread loads 16 floats (half a row of the K-tile)
    const int srow = tid >> 1;            // 0..127
    const int skh  = (tid & 1) * 16;      // k offset within tile
    const float* xg = x + (size_t)(b0 + srow) * DD + skh;
    const int jtree = t0 + (srow >> 6);
    const int jnode = srow & 63;
    const bool wvalid = jnode < NN;
    const float* wg = sw + ((size_t)jtree * NN + (wvalid ? jnode : 0)) * DD + skh;

    float4 xv[4], wv[4];
#pragma unroll
    for (int i = 0; i < 4; ++i) {
        xv[i] = *(const float4*)(xg + i * 4);
        wv[i] = wvalid ? *(const float4*)(wg + i * 4) : float4{0.f, 0.f, 0.f, 0.f};
    }

    for (int k0 = 0; k0 < DD; k0 += BK) {
        __syncthreads();   // previous tile's frag reads done
        // convert fp32 -> fp16, 16B vector stores to LDS
        f16x8 hx0, hx1, hw0, hw1;
        hx0[0]=(_Float16)xv[0].x; hx0[1]=(_Float16)xv[0].y; hx0[2]=(_Float16)xv[0].z; hx0[3]=(_Float16)xv[0].w;
        hx0[4]=(_Float16)xv[1].x; hx0[5]=(_Float16)xv[1].y; hx0[6]=(_Float16)xv[1].z; hx0[7]=(_Float16)xv[1].w;
        hx1[0]=(_Float16)xv[2].x; hx1[1]=(_Float16)xv[2].y; hx1[2]=(_Float16)xv[2].z; hx1[3]=(_Float16)xv[2].w;
        hx1[4]=(_Float16)xv[3].x; hx1[5]=(_Float16)xv[3].y; hx1[6]=(_Float16)xv[3].z; hx1[7]=(_Float16)xv[3].w;
        hw0[0]=(_Float16)wv[0].x; hw0[1]=(_Float16)wv[0].y; hw0[2]=(_Float16)wv[0].z; hw0[3]=(_Float16)wv[0].w;
        hw0[4]=(_Float16)wv[1].x; hw0[5]=(_Float16)wv[1].y; hw0[6]=(_Float16)wv[1].z; hw0[7]=(_Float16)wv[1].w;
        hw1[0]=(_Float16)wv[2].x; hw1[1]=(_Float16)wv[2].y; hw1[2]=(_Float16)wv[2].z; hw1[3]=(_Float16)wv[2].w;
        hw1[4]=(_Float16)wv[3].x; hw1[5]=(_Float16)wv[3].y; hw1[6]=(_Float16)wv[3].z; hw1[7]=(_Float16)wv[3].w;
        *(f16x8*)&xs[srow * XSTR + skh]     = hx0;
        *(f16x8*)&xs[srow * XSTR + skh + 8] = hx1;
        *(f16x8*)&wl[srow * XSTR + skh]     = hw0;
        *(f16x8*)&wl[srow * XSTR + skh + 8] = hw1;
        __syncthreads();
        if (k0 + BK < DD) {   // prefetch next tile under compute
#pragma unroll
            for (int i = 0; i < 4; ++i) {
                xv[i] = *(const float4*)(xg + k0 + BK + i * 4);
                wv[i] = wvalid ? *(const float4*)(wg + k0 + BK + i * 4)
                               : float4{0.f, 0.f, 0.f, 0.f};
            }
        }
        // fragment loads + 16 MFMA (16x16x32 f16, m89-verified layouts)
        f16x8 af[4], bf[4];
#pragma unroll
        for (int mi = 0; mi < 4; ++mi)
            af[mi] = *(const f16x8*)&xs[(64 * wy + 16 * mi + l15) * XSTR + quad * 8];
#pragma unroll
        for (int ni = 0; ni < 4; ++ni)
            bf[ni] = *(const f16x8*)&wl[(64 * wx + 16 * ni + l15) * XSTR + quad * 8];
#pragma unroll
        for (int mi = 0; mi < 4; ++mi)
#pragma unroll
            for (int ni = 0; ni < 4; ++ni)
                acc[mi][ni] = __builtin_amdgcn_mfma_f32_16x16x32_f16(
                    af[mi], bf[ni], acc[mi][ni], 0, 0, 0);
    }
    __syncthreads();   // staging region about to be reused (lp aliases xs)

    // --- sigmoid -> dec[row][col] f16 ---
#pragma unroll
    for (int mi = 0; mi < 4; ++mi) {
        int r0 = 64 * wy + 16 * mi + quad * 4;
#pragma unroll
        for (int ni = 0; ni < 4; ++ni) {
            int col = 64 * wx + 16 * ni + l15;
            float bsv = bias_s[col];
#pragma unroll
            for (int r = 0; r < 4; ++r) {
                float lg = acc[mi][ni][r] + bsv;
                dec[(r0 + r) * DSTR + col] = (_Float16)(1.f / (1.f + __expf(-lg)));
            }
        }
    }
    __syncthreads();

    // --- per tree: leaf probs -> lp LDS (A-frag layout) -> MFMA GEMM2 ---
    floatx4 oacc[2][7];
#pragma unroll
    for (int mi = 0; mi < 2; ++mi)
#pragma unroll
        for (int ni = 0; ni < 7; ++ni) oacc[mi][ni] = (floatx4)0.f;

    const int lrow = tid >> 1;        // 0..127
    const int half = tid & 1;         // leaf group 0..31 / 32..63

    for (int tt = 0; tt < 2; ++tt) {
        const _Float16* dr = &dec[lrow * DSTR + tt * 64];
        float d0 = (float)dr[0];
        float p1 = half ? d0 : 1.f - d0;
        float d1 = (float)dr[1 + half];
#pragma unroll
        for (int b8 = 0; b8 < 4; ++b8) {
            int i4 = b8 >> 1, i3 = b8 & 1;
            float p2 = p1 * (i4 ? d1 : 1.f - d1);
            float d2 = (float)dr[3 + 2 * half + i4];
            float p3 = p2 * (i3 ? d2 : 1.f - d2);
            float d3 = (float)dr[7 + 4 * half + b8];
            f16x8 blk;
#pragma unroll
            for (int i2 = 0; i2 < 2; ++i2) {
                float p4 = p3 * (i2 ? d3 : 1.f - d3);
                float d4 = (float)dr[15 + 8 * half + 2 * b8 + i2];
#pragma unroll
                for (int i1 = 0; i1 < 2; ++i1) {
                    float p5 = p4 * (i1 ? d4 : 1.f - d4);
                    float d5 = (float)dr[31 + 16 * half + 4 * b8 + 2 * i2 + i1];
                    blk[i2 * 4 + i1 * 2 + 0] = (_Float16)(p5 * (1.f - d5));
                    blk[i2 * 4 + i1 * 2 + 1] = (_Float16)(p5 * d5);
                }
            }
            *(f16x8*)&lp[lrow * LPSTR + half * 32 + b8 * 8] = blk;
        }
        __syncthreads();   // lp written

        // GEMM2: wave handles rows 32*wid..+31, all 112 cols; K=64 (2 steps)
        const _Float16* w2p = w2T + (size_t)(t0 + tt) * CPAD * LL;
#pragma unroll
        for (int ks = 0; ks < 2; ++ks) {
            f16x8 a2[2];
#pragma unroll
            for (int mi = 0; mi < 2; ++mi)
                a2[mi] = *(const f16x8*)&lp[(32 * wid + 16 * mi + l15) * LPSTR
                                            + ks * 32 + quad * 8];
#pragma unroll
            for (int ni = 0; ni < 7; ++ni) {
                f16x8 b2 = *(const f16x8*)(w2p + (size_t)(16 * ni + l15) * LL
                                           + ks * 32 + quad * 8);
#pragma unroll
                for (int mi = 0; mi < 2; ++mi)
                    oacc[mi][ni] = __builtin_amdgcn_mfma_f32_16x16x32_f16(
                        a2[mi], b2, oacc[mi][ni], 0, 0, 0);
            }
        }
        __syncthreads();   // lp reads done before next tree overwrites
    }

    // --- atomic epilogue: one add per (row, class) per tree-pair block ---
#pragma unroll
    for (int ni = 0; ni < 7; ++ni) {
        int c = 16 * ni + l15;
        if (c < CC) {
#pragma unroll
            for (int mi = 0; mi < 2; ++mi) {
                int r0 = 32 * wid + 16 * mi + quad * 4;
#pragma unroll
                for (int r = 0; r < 4; ++r)
                    atomicAdd(&out[(size_t)(b0 + r0 + r) * CC + c], oacc[mi][ni][r]);
            }
        }
    }
}

// ---------------------------------------------------------------------------
extern "C" void kernel_launch(void* const* d_in, const int* in_sizes, int n_in,
                              void* d_out, int out_size, void* d_ws, size_t ws_size,
                              hipStream_t stream) {
    const float* x  = (const float*)d_in[0];   // [8192][512]
    const float* sw = (const float*)d_in[1];   // [64][63][512]
    const float* sb = (const float*)d_in[2];   // [64][63]
    const float* ll = (const float*)d_in[3];   // [64][64][100]
    const float* tw = (const float*)d_in[4];   // [64]
    float* out = (float*)d_out;                // [8192][100]
    _Float16* w2T = (_Float16*)d_ws;           // [64][112][64] f16 = 0.92 MB

    hipMemsetAsync(d_out, 0, (size_t)out_size * sizeof(float), stream);
    prep_w2_kernel<<<dim3(TREES * LL / 4), 256, 0, stream>>>(ll, tw, w2T);
    forest_kernel<<<dim3(BB / BM, TREES / 2), 256, 0, stream>>>(x, sw, sb, w2T, out);
}

// Round 3
// 272.319 us; speedup vs baseline: 2.5546x; 1.0644x over previous
//
#include <hip/hip_runtime.h>

#define TREES 64
#define NN 63        // internal nodes per tree
#define LL 64        // leaves per tree
#define CC 100       // classes
#define CPAD 112     // classes padded to 7*16
#define DD 512       // feature dim
#define BB 8192      // batch
#define BM 128       // rows per block
#define BK 32        // K tile

typedef __attribute__((ext_vector_type(8))) _Float16 f16x8;
typedef __attribute__((ext_vector_type(4))) float floatx4;

// LDS map (bytes). Staging xs/wl: stride 32 f16, XOR-swizzled 16B chunks
// (chunk' = chunk ^ (row&3)) -> conflict-bounded, no padding, 16B-aligned.
// lp: stride 64 f16, swizzle chunk ^ (row&7), aliases dead staging region.
// dec: stride 66 f16 (rows map to distinct banks). w2b: stride 72 f16.
#define XS_OFF 0                 // 128*32*2 = 8192
#define WL_OFF 8192              // 128*32*2 = 8192
#define LP_OFF 0                 // 128*64*2 = 16384 (aliases xs+wl)
#define DEC_OFF 16384            // 128*66*2 = 16896
#define W2B_OFF 33280            // 112*72*2 = 16128
#define SMEM_BYTES 49408         // *3 = 148224 <= 160 KiB -> 3 blocks/CU

// ---------------------------------------------------------------------------
// Kernel 1: w2T[t][c][l] = f16( tree_w[t] * softmax(leaf_logits[t,l,:])[c] )
// ---------------------------------------------------------------------------
__global__ __launch_bounds__(256) void prep_w2_kernel(
    const float* __restrict__ leaf_logits,
    const float* __restrict__ tree_w,
    _Float16* __restrict__ w2T)
{
    int row  = blockIdx.x * 4 + (threadIdx.x >> 6);   // 0..4095 (= t*64 + l)
    int lane = threadIdx.x & 63;
    int t = row >> 6, l = row & 63;
    const float* src = leaf_logits + (size_t)row * CC;
    float v0 = (lane < CC)      ? src[lane]      : -1e30f;
    float v1 = (lane + 64 < CC) ? src[lane + 64] : -1e30f;
    float m = fmaxf(v0, v1);
#pragma unroll
    for (int off = 32; off > 0; off >>= 1)
        m = fmaxf(m, __shfl_down(m, off, 64));
    m = __shfl(m, 0, 64);
    float e0 = (lane < CC)      ? __expf(v0 - m) : 0.f;
    float e1 = (lane + 64 < CC) ? __expf(v1 - m) : 0.f;
    float s = e0 + e1;
#pragma unroll
    for (int off = 32; off > 0; off >>= 1)
        s += __shfl_down(s, off, 64);
    s = __shfl(s, 0, 64);
    float scale = tree_w[t] / s;
    _Float16* base = w2T + (size_t)t * CPAD * LL;
    if (lane < CC)      base[(size_t)lane * LL + l]        = (_Float16)(e0 * scale);
    if (lane + 64 < CC) base[(size_t)(lane + 64) * LL + l] = (_Float16)(e1 * scale);
    if (lane < CPAD - CC) base[(size_t)(CC + lane) * LL + l] = (_Float16)0.f;
}

// ---------------------------------------------------------------------------
// Kernel 2: fused fp16-MFMA dec-GEMM -> sigmoid -> leaf probs -> MFMA GEMM2
// grid = (B/BM, TREES/2); block = 256 (4 waves, 2x2, wave tile 64x64)
// ---------------------------------------------------------------------------
__global__ __launch_bounds__(256, 3) void forest_kernel(
    const float* __restrict__ x,     // [B][D]
    const float* __restrict__ sw,    // [T][63][D]
    const float* __restrict__ sb,    // [T][63]
    const _Float16* __restrict__ w2T,// [T][112][64]  (ws)
    float* __restrict__ out)         // [B][100]
{
    __shared__ __align__(16) char smem[SMEM_BYTES];
    _Float16* xs  = (_Float16*)(smem + XS_OFF);
    _Float16* wl  = (_Float16*)(smem + WL_OFF);
    _Float16* lp  = (_Float16*)(smem + LP_OFF);
    _Float16* dec = (_Float16*)(smem + DEC_OFF);
    _Float16* w2b = (_Float16*)(smem + W2B_OFF);

    const int tid  = threadIdx.x;
    const int lane = tid & 63;
    const int wid  = tid >> 6;
    const int wy   = wid >> 1;      // wave row group
    const int wx   = wid & 1;       // wave col group (tree within pair)
    const int quad = lane >> 4;     // 0..3
    const int l15  = lane & 15;
    const int b0   = blockIdx.x * BM;
    const int t0   = blockIdx.y * 2;

    // bias registers for this wave's tree (cols 16*ni + l15)
    float bias_v[4];
    {
        int tr = t0 + wx;
#pragma unroll
        for (int ni = 0; ni < 4; ++ni) {
            int nd = 16 * ni + l15;
            bias_v[ni] = (nd < NN) ? sb[tr * NN + nd] : 0.f;
        }
    }

    floatx4 acc[4][4];
#pragma unroll
    for (int i = 0; i < 4; ++i)
#pragma unroll
        for (int j = 0; j < 4; ++j) acc[i][j] = (floatx4)0.f;

    // staging mapping: each thread loads 16 floats (half a row of the K-tile)
    const int srow = tid >> 1;            // 0..127
    const int skh  = (tid & 1) * 16;      // k offset within tile (f32/f16 elems)
    const int q0   = (tid & 1) * 2;       // logical 16B chunk indices q0, q0+1
    const int swz0 = (q0 ^ (srow & 3)) * 8;
    const int swz1 = ((q0 + 1) ^ (srow & 3)) * 8;
    const float* xg = x + (size_t)(b0 + srow) * DD + skh;
    const int jtree = t0 + (srow >> 6);
    const int jnode = srow & 63;
    const bool wvalid = jnode < NN;
    const float* wg = sw + ((size_t)jtree * NN + (wvalid ? jnode : 0)) * DD + skh;

    float4 xv[4], wv[4];
#pragma unroll
    for (int i = 0; i < 4; ++i) {
        xv[i] = *(const float4*)(xg + i * 4);
        wv[i] = wvalid ? *(const float4*)(wg + i * 4) : float4{0.f, 0.f, 0.f, 0.f};
    }

    for (int k0 = 0; k0 < DD; k0 += BK) {
        __syncthreads();   // previous tile's frag reads done
        f16x8 hx0, hx1, hw0, hw1;
        hx0[0]=(_Float16)xv[0].x; hx0[1]=(_Float16)xv[0].y; hx0[2]=(_Float16)xv[0].z; hx0[3]=(_Float16)xv[0].w;
        hx0[4]=(_Float16)xv[1].x; hx0[5]=(_Float16)xv[1].y; hx0[6]=(_Float16)xv[1].z; hx0[7]=(_Float16)xv[1].w;
        hx1[0]=(_Float16)xv[2].x; hx1[1]=(_Float16)xv[2].y; hx1[2]=(_Float16)xv[2].z; hx1[3]=(_Float16)xv[2].w;
        hx1[4]=(_Float16)xv[3].x; hx1[5]=(_Float16)xv[3].y; hx1[6]=(_Float16)xv[3].z; hx1[7]=(_Float16)xv[3].w;
        hw0[0]=(_Float16)wv[0].x; hw0[1]=(_Float16)wv[0].y; hw0[2]=(_Float16)wv[0].z; hw0[3]=(_Float16)wv[0].w;
        hw0[4]=(_Float16)wv[1].x; hw0[5]=(_Float16)wv[1].y; hw0[6]=(_Float16)wv[1].z; hw0[7]=(_Float16)wv[1].w;
        hw1[0]=(_Float16)wv[2].x; hw1[1]=(_Float16)wv[2].y; hw1[2]=(_Float16)wv[2].z; hw1[3]=(_Float16)wv[2].w;
        hw1[4]=(_Float16)wv[3].x; hw1[5]=(_Float16)wv[3].y; hw1[6]=(_Float16)wv[3].z; hw1[7]=(_Float16)wv[3].w;
        *(f16x8*)&xs[srow * 32 + swz0] = hx0;
        *(f16x8*)&xs[srow * 32 + swz1] = hx1;
        *(f16x8*)&wl[srow * 32 + swz0] = hw0;
        *(f16x8*)&wl[srow * 32 + swz1] = hw1;
        __syncthreads();
        if (k0 + BK < DD) {   // prefetch next tile under compute
#pragma unroll
            for (int i = 0; i < 4; ++i) {
                xv[i] = *(const float4*)(xg + k0 + BK + i * 4);
                wv[i] = wvalid ? *(const float4*)(wg + k0 + BK + i * 4)
                               : float4{0.f, 0.f, 0.f, 0.f};
            }
        }
        f16x8 af[4], bf[4];
#pragma unroll
        for (int mi = 0; mi < 4; ++mi) {
            int r = 64 * wy + 16 * mi + l15;
            af[mi] = *(const f16x8*)&xs[r * 32 + ((quad ^ (r & 3)) * 8)];
        }
#pragma unroll
        for (int ni = 0; ni < 4; ++ni) {
            int r = 64 * wx + 16 * ni + l15;
            bf[ni] = *(const f16x8*)&wl[r * 32 + ((quad ^ (r & 3)) * 8)];
        }
#pragma unroll
        for (int mi = 0; mi < 4; ++mi)
#pragma unroll
            for (int ni = 0; ni < 4; ++ni)
                acc[mi][ni] = __builtin_amdgcn_mfma_f32_16x16x32_f16(
                    af[mi], bf[ni], acc[mi][ni], 0, 0, 0);
    }

    // ------------------- tree-sequential epilogue -------------------
    floatx4 oacc[2][7];
#pragma unroll
    for (int mi = 0; mi < 2; ++mi)
#pragma unroll
        for (int ni = 0; ni < 7; ++ni) oacc[mi][ni] = (floatx4)0.f;

    const int lrow = tid >> 1;        // 0..127
    const int half = tid & 1;         // leaf group 0..31 / 32..63

    for (int tt = 0; tt < 2; ++tt) {
        if (tt) __syncthreads();   // GEMM2(t0) reads done -> w2b/lp reusable

        // stage this tree's w2T slice [112][64] -> w2b stride 72 (16B chunks)
        {
            const _Float16* w2p = w2T + (size_t)(t0 + tt) * CPAD * LL;
#pragma unroll
            for (int j = 0; j < 4; ++j) {
                int idx = tid + j * 256;          // 896 chunks total
                if (idx < CPAD * 8) {
                    int c = idx >> 3, q = idx & 7;
                    f16x8 v = *(const f16x8*)(w2p + c * LL + q * 8);
                    *(f16x8*)&w2b[c * 72 + q * 8] = v;
                }
            }
        }
        // this tree's decisions -> dec[row][node], stride 66
        if (wx == tt) {
#pragma unroll
            for (int mi = 0; mi < 4; ++mi) {
                int r0 = 64 * wy + 16 * mi + quad * 4;
#pragma unroll
                for (int ni = 0; ni < 4; ++ni) {
                    int col = 16 * ni + l15;
                    float bsv = bias_v[ni];
#pragma unroll
                    for (int r = 0; r < 4; ++r) {
                        float lg = acc[mi][ni][r] + bsv;
                        dec[(r0 + r) * 66 + col] = (_Float16)(1.f / (1.f + __expf(-lg)));
                    }
                }
            }
        }
        __syncthreads();   // dec + w2b visible; staging frag reads done (tt=0)

        // leaf probs for this tree -> lp (swizzled A-frag friendly layout)
        {
            const _Float16* dr = &dec[lrow * 66];
            float d0 = (float)dr[0];
            float p1 = half ? d0 : 1.f - d0;
            float d1 = (float)dr[1 + half];
#pragma unroll
            for (int b8 = 0; b8 < 4; ++b8) {
                int i4 = b8 >> 1, i3 = b8 & 1;
                float p2 = p1 * (i4 ? d1 : 1.f - d1);
                float d2 = (float)dr[3 + 2 * half + i4];
                float p3 = p2 * (i3 ? d2 : 1.f - d2);
                float d3 = (float)dr[7 + 4 * half + b8];
                f16x8 blk;
#pragma unroll
                for (int i2 = 0; i2 < 2; ++i2) {
                    float p4 = p3 * (i2 ? d3 : 1.f - d3);
                    float d4 = (float)dr[15 + 8 * half + 2 * b8 + i2];
#pragma unroll
                    for (int i1 = 0; i1 < 2; ++i1) {
                        float p5 = p4 * (i1 ? d4 : 1.f - d4);
                        float d5 = (float)dr[31 + 16 * half + 4 * b8 + 2 * i2 + i1];
                        blk[i2 * 4 + i1 * 2 + 0] = (_Float16)(p5 * (1.f - d5));
                        blk[i2 * 4 + i1 * 2 + 1] = (_Float16)(p5 * d5);
                    }
                }
                int qlog = half * 4 + b8;
                *(f16x8*)&lp[lrow * 64 + ((qlog ^ (lrow & 7)) * 8)] = blk;
            }
        }
        __syncthreads();   // lp written

        // GEMM2: wave rows 32*wid..+31, 112 cols, K=64 (2 steps), B from LDS
#pragma unroll
        for (int ks = 0; ks < 2; ++ks) {
            f16x8 a2[2];
#pragma unroll
            for (int mi = 0; mi < 2; ++mi) {
                int r = 32 * wid + 16 * mi + l15;
                int qlog = ks * 4 + quad;
                a2[mi] = *(const f16x8*)&lp[r * 64 + ((qlog ^ (r & 7)) * 8)];
            }
#pragma unroll
            for (int ni = 0; ni < 7; ++ni) {
                f16x8 b2 = *(const f16x8*)&w2b[(16 * ni + l15) * 72 + ks * 32 + quad * 8];
#pragma unroll
                for (int mi = 0; mi < 2; ++mi)
                    oacc[mi][ni] = __builtin_amdgcn_mfma_f32_16x16x32_f16(
                        a2[mi], b2, oacc[mi][ni], 0, 0, 0);
            }
        }
    }

    // --- atomic epilogue: one add per (row, class) per tree-pair block ---
#pragma unroll
    for (int ni = 0; ni < 7; ++ni) {
        int c = 16 * ni + l15;
        if (c < CC) {
#pragma unroll
            for (int mi = 0; mi < 2; ++mi) {
                int r0 = 32 * wid + 16 * mi + quad * 4;
#pragma unroll
                for (int r = 0; r < 4; ++r)
                    atomicAdd(&out[(size_t)(b0 + r0 + r) * CC + c], oacc[mi][ni][r]);
            }
        }
    }
}

// ---------------------------------------------------------------------------
extern "C" void kernel_launch(void* const* d_in, const int* in_sizes, int n_in,
                              void* d_out, int out_size, void* d_ws, size_t ws_size,
                              hipStream_t stream) {
    const float* x  = (const float*)d_in[0];   // [8192][512]
    const float* sw = (const float*)d_in[1];   // [64][63][512]
    const float* sb = (const float*)d_in[2];   // [64][63]
    const float* ll = (const float*)d_in[3];   // [64][64][100]
    const float* tw = (const float*)d_in[4];   // [64]
    float* out = (float*)d_out;                // [8192][100]
    _Float16* w2T = (_Float16*)d_ws;           // [64][112][64] f16 = 0.92 MB

    hipMemsetAsync(d_out, 0, (size_t)out_size * sizeof(float), stream);
    prep_w2_kernel<<<dim3(TREES * LL / 4), 256, 0, stream>>>(ll, tw, w2T);
    forest_kernel<<<dim3(BB / BM, TREES / 2), 256, 0, stream>>>(x, sw, sb, w2T, out);
}